// Round 13
// baseline (76.898 us; speedup 1.0000x reference)
//
#include <hip/hip_runtime.h>

typedef __attribute__((ext_vector_type(8)))  short short8;
typedef __attribute__((ext_vector_type(16))) float f32x16;
typedef unsigned int uint;
typedef __attribute__((ext_vector_type(4))) uint u32x4;

#define SEQ 2048

__device__ inline uint pack2(float lo, float hi_) {
    uint ul = __float_as_uint(lo), uh = __float_as_uint(hi_);
    ul = (ul + 0x7fffu + ((ul >> 16) & 1u)) >> 16;   // RNE f32->bf16
    uh = (uh + 0x7fffu + ((uh >> 16) & 1u)) >> 16;
    return (ul & 0xffffu) | (uh << 16);
}

#define MFMA(A, B, C) __builtin_amdgcn_mfma_f32_32x32x16_bf16( \
    __builtin_bit_cast(short8, A), __builtin_bit_cast(short8, B), C, 0, 0, 0)

// ============================ VMEM-A variant =============================
// A-frags from a per-row bf16 x copy in d_ws via buffer_load (SRD bounds-check
// = free causal zeros); B-frags from 2 LDS krev parity copies.
// DEPTH-3 circular register pipeline, counted vmcnt(8), launch_bounds(128,3)
// so the A-slot registers NEVER spill (spill scratch ops would corrupt the
// manual vmcnt bookkeeping -> r12's NaN).

#define KSTR2 1040
#define LDSU  2080                 // kA[1040] + kB[1040]; reused as exchange
#define EX0   0
#define EX1   1024

__global__ __launch_bounds__(128, 3)
void hyena_vmem(const float* __restrict__ x, const float* __restrict__ kern,
                const float* __restrict__ bias, float* __restrict__ out,
                char* __restrict__ ws)
{
    __shared__ __align__(16) uint lds[LDSU];
    char* ldsb = (char*)lds;

    const int tid = threadIdx.x;       // 0..127
    const int wv  = tid >> 6;          // wave id 0,1
    const int l   = tid & 63;
    const int n   = l & 31;            // MFMA row (A) / col (B/D)
    const int hi  = l >> 5;            // k-group half
    const int row = blockIdx.x;        // b*2048 + d
    const size_t rb = (size_t)row * SEQ;
    const float bv = bias[row & 2047];

    char* wsrow = ws + (size_t)row * 4096;      // this row's bf16 x (4 KB)
    u32x4 rsrc;                                  // SRD: base, stride0, 4096B, raw
    {
        unsigned long long a = (unsigned long long)wsrow;
        rsrc[0] = (uint)a; rsrc[1] = (uint)(a >> 32);
        rsrc[2] = 4096u;   rsrc[3] = 0x00020000u;
    }

    // ---- pack x row to bf16 in ws (coalesced dwordx4 stores) ----
    #pragma unroll
    for (int it = 0; it < 2; ++it) {
        const int e = it * 1024 + 8 * tid;       // 0..2040 step 8
        float4 a = *(const float4*)&x[rb + e];
        float4 b = *(const float4*)&x[rb + e + 4];
        u32x4 w = {pack2(a.x, a.y), pack2(a.z, a.w), pack2(b.x, b.y), pack2(b.z, b.w)};
        *(u32x4*)(wsrow + 2 * e) = w;
    }
    // ---- stage 2 krev parity copies: kA[m]=(kr[2m],kr[2m+1]), kB[m]=(kr[2m+1],kr[2m+2])
    {
        const int j = 8 * tid;
        #pragma unroll
        for (int it = 0; it < 2; ++it) {
            const int jj = it * 1024 + j;                     // 0..2040 step 8
            const float* kp0 = &kern[rb + (jj == 2040 ? 0 : (2036 - jj))];
            const float* kp1 = &kern[rb + (2040 - jj)];
            float4 f0 = *(const float4*)kp0;                  // (kr[jj+11..jj+8]) desc
            float4 f1 = *(const float4*)kp1;                  // (kr[jj+7..jj+4])  desc
            float4 f2 = *(const float4*)(kp1 + 4);            // (kr[jj+3..jj])    desc
            if (jj == 2040) { f0.x = 0.f; f0.y = 0.f; f0.z = 0.f; f0.w = 0.f; }
            const float k0 = f2.w, k1 = f2.z, k2 = f2.y, k3 = f2.x;
            const float k4 = f1.w, k5 = f1.z, k6 = f1.y, k7 = f1.x;
            const float k8 = f0.w;
            const int m = jj >> 1;
            u32x4 w0 = {pack2(k0,k1), pack2(k2,k3), pack2(k4,k5), pack2(k6,k7)};
            u32x4 w1 = {pack2(k1,k2), pack2(k3,k4), pack2(k5,k6), pack2(k7,k8)};
            *(u32x4*)&lds[m]        = w0;
            *(u32x4*)&lds[1040 + m] = w1;
        }
    }
    if (tid < 16) {                    // tails (elements >= 2048 are zero)
        lds[1024 + tid]        = 0u;
        lds[1040 + 1024 + tid] = 0u;
    }
    asm volatile("" :: "v"(bv));       // materialize bias load BEFORE counted region
    asm volatile("s_waitcnt vmcnt(0)" ::: "memory");   // ws writes visible in L2
    __syncthreads();

    // ---- per-lane bases (wave wv handles r = R0 .. R0+15) ----
    const int R0   = wv << 4;
    const int st00 = 2047 - n + 8 * hi;
    const int par  = st00 & 1;
    int kb  = (par * KSTR2 + (st00 >> 1)) * 4 - 2048 - (R0 << 6);  // T_{r+32} byte base
    int kbh = kb + 2048;                                           // T_r byte base
    asm volatile("" : "+v"(kbh));      // independent base -> ds_read2 merging
    uint voff0 = (uint)(64 * (n - R0) + 16 * hi);  // "negative" -> OOB -> zeros
    uint voff1 = voff0 + 2048u;

    f32x16 acc0 = {}, acc1a = {}, acc1b = {};
    u32x4 A00[3], A01[3], A10[3], A11[3];          // 3-slot circular pipeline

    #define ISSUE_A(buf, v0, v1)                                                     \
        asm volatile("buffer_load_dwordx4 %0, %1, %2, 0 offen"                       \
                     : "=v"(A00[buf]) : "v"(v0), "s"(rsrc));                         \
        asm volatile("buffer_load_dwordx4 %0, %1, %2, 0 offen offset:32"             \
                     : "=v"(A01[buf]) : "v"(v0), "s"(rsrc));                         \
        asm volatile("buffer_load_dwordx4 %0, %1, %2, 0 offen"                       \
                     : "=v"(A10[buf]) : "v"(v1), "s"(rsrc));                         \
        asm volatile("buffer_load_dwordx4 %0, %1, %2, 0 offen offset:32"             \
                     : "=v"(A11[buf]) : "v"(v1), "s"(rsrc));

    // prologue: fill 3 slots (12 loads in flight)
    ISSUE_A(0, voff0, voff1)  voff0 -= 64u; voff1 -= 64u;
    ISSUE_A(1, voff0, voff1)  voff0 -= 64u; voff1 -= 64u;
    ISSUE_A(2, voff0, voff1)  voff0 -= 64u; voff1 -= 64u;

    #pragma unroll
    for (int i = 0; i < 16; ++i) {
        const int s = i % 3;                 // unrolled -> compile-time constant
        // retire exactly the oldest slot; keep up to 8 loads in flight (T4)
        if (i <= 13)      asm volatile("s_waitcnt vmcnt(8)");
        else if (i == 14) asm volatile("s_waitcnt vmcnt(4)");
        else              asm volatile("s_waitcnt vmcnt(0)");
        __builtin_amdgcn_sched_barrier(0);   // rule #18: pin consumers below wait

        const uint* kl = (const uint*)(ldsb + kb);           // T_{r+32}
        const uint* kh = (const uint*)(ldsb + kbh);          // T_r
        u32x4 b00 = {kh[0], kh[1], kh[2],  kh[3]};           // s0
        u32x4 b01 = {kh[8], kh[9], kh[10], kh[11]};          // s1
        u32x4 b10 = {kl[0], kl[1], kl[2],  kl[3]};
        u32x4 b11 = {kl[8], kl[9], kl[10], kl[11]};

        acc0  = MFMA(A00[s], b00, acc0);    // tile0 += X(-r)   * T_r^T
        acc1a = MFMA(A10[s], b00, acc1a);   // tile1 += X(32-r) * T_r^T
        acc0  = MFMA(A01[s], b01, acc0);
        acc1a = MFMA(A11[s], b01, acc1a);
        acc1b = MFMA(A00[s], b10, acc1b);   // tile1 += X(-r)   * T_{r+32}^T
        acc1b = MFMA(A01[s], b11, acc1b);

        if (i < 13) {                        // refill this slot for iter i+3
            ISSUE_A(s, voff0, voff1)
            voff0 -= 64u; voff1 -= 64u;
        }
        kb -= 64; kbh -= 64;                 // shift -32 krev elements
    }
    __syncthreads();     // all k reads done before exchange overwrites copies

    // ---- cross-wave partial exchange ([q][lane] f4 layout) ----
    f32x16 part_send, part_keep;
    if (wv == 0) { part_send = acc1a + acc1b; part_keep = acc0; }
    else         { part_send = acc0;          part_keep = acc1a + acc1b; }
    const int exw = (wv == 0) ? EX0 : EX1;
    const int exr = (wv == 0) ? EX1 : EX0;
    #pragma unroll
    for (int q = 0; q < 4; ++q) {
        float4 f = {part_send[4*q], part_send[4*q+1], part_send[4*q+2], part_send[4*q+3]};
        *(float4*)&lds[exw + q * 256 + 4 * l] = f;
    }
    __syncthreads();
    f32x16 tile = part_keep;
    #pragma unroll
    for (int q = 0; q < 4; ++q) {
        float4 f = *(const float4*)&lds[exr + q * 256 + 4 * l];
        tile[4*q] += f.x; tile[4*q+1] += f.y; tile[4*q+2] += f.z; tile[4*q+3] += f.w;
    }

    // ---- epilogue: residual x (bf16) via buffer_load_ushort from L2-hot ws ----
    uint xr16[16];
    const uint voffr = (uint)(2048 * wv + 256 * hi + 2 * n);
    #define LOADR(t)                                                              \
        asm volatile("buffer_load_ushort %0, %1, %2, 0 offen offset:%3"           \
                     : "=v"(xr16[t]) : "v"(voffr), "s"(rsrc),                     \
                       "i"(64 * (((t) & 3) + 8 * ((t) >> 2))));
    LOADR(0)  LOADR(1)  LOADR(2)  LOADR(3)  LOADR(4)  LOADR(5)  LOADR(6)  LOADR(7)
    LOADR(8)  LOADR(9)  LOADR(10) LOADR(11) LOADR(12) LOADR(13) LOADR(14) LOADR(15)
    asm volatile("s_waitcnt vmcnt(0)");
    __builtin_amdgcn_sched_barrier(0);

    #pragma unroll
    for (int t = 0; t < 16; ++t) {
        const int rloc = (t & 3) + 8 * (t >> 2) + 4 * hi;   // verified 32x32 C/D map
        const int p = 32 * wv + rloc;
        const float xr = __uint_as_float(xr16[t] << 16);
        out[rb + (size_t)p * 32 + n] = tile[t] + xr + bv;
    }
}

// ====================== LDS fallback (r10, proven) =======================
#define KB0f   1024
#define KSTR2f 1040
#define KB1f   (KB0f + KSTR2f)
#define ZBf    (KB0f + 2 * KSTR2f)
#define LDSUf  (ZBf + 16)

__device__ inline int swzf(int v) { return v ^ ((v >> 3) & 28); }

__global__ __launch_bounds__(128, 6)
void hyena_lds(const float* __restrict__ x, const float* __restrict__ kern,
               const float* __restrict__ bias, float* __restrict__ out)
{
    __shared__ __align__(16) uint lds[LDSUf];
    char* ldsb = (char*)lds;

    const int tid = threadIdx.x;
    const int wv  = tid >> 6;
    const int l   = tid & 63;
    const int n   = l & 31;
    const int hi  = l >> 5;
    const int row = blockIdx.x;
    const size_t rb = (size_t)row * SEQ;
    const float bv = bias[row & 2047];

    #pragma unroll
    for (int it = 0; it < 2; ++it) {
        const int e = it * 1024 + 8 * tid;
        float4 a = *(const float4*)&x[rb + e];
        float4 b = *(const float4*)&x[rb + e + 4];
        uint4 w = {pack2(a.x, a.y), pack2(a.z, a.w), pack2(b.x, b.y), pack2(b.z, b.w)};
        *(uint4*)&lds[swzf(e >> 1)] = w;
    }
    #pragma unroll
    for (int it = 0; it < 2; ++it) {
        const int j = it * 1024 + 8 * tid;
        const float* kp0 = &kern[rb + (j == 2040 ? 0 : (2036 - j))];
        const float* kp1 = &kern[rb + (2040 - j)];
        float4 f0 = *(const float4*)kp0;
        float4 f1 = *(const float4*)kp1;
        float4 f2 = *(const float4*)(kp1 + 4);
        if (j == 2040) { f0.x = 0.f; f0.y = 0.f; f0.z = 0.f; f0.w = 0.f; }
        const float k0 = f2.w, k1 = f2.z, k2 = f2.y, k3 = f2.x;
        const float k4 = f1.w, k5 = f1.z, k6 = f1.y, k7 = f1.x;
        const float k8 = f0.w;
        const int m = j >> 1;
        uint4 w0 = {pack2(k0,k1), pack2(k2,k3), pack2(k4,k5), pack2(k6,k7)};
        uint4 w1 = {pack2(k1,k2), pack2(k3,k4), pack2(k5,k6), pack2(k7,k8)};
        *(uint4*)&lds[KB0f + m] = w0;
        *(uint4*)&lds[KB1f + m] = w1;
    }
    if (tid < 16) {
        lds[KB0f + 1024 + tid] = 0u;
        lds[KB1f + 1024 + tid] = 0u;
        lds[ZBf + tid] = 0u;
    }
    __syncthreads();

    const int R0   = wv << 4;
    const int st00 = 2047 - n + 8 * hi;
    const int par  = st00 & 1;
    int kb  = (KB0f + par * KSTR2f + (st00 >> 1)) * 4 - 2048 - (R0 << 6);
    int kbh = kb + 2048;
    asm volatile("" : "+v"(kbh));
    int ua = 16 * n + 4 * hi - (R0 << 4);
    const int zb0 = ZBf * 4 + 16 * hi;

    f32x16 acc0 = {}, acc1a = {}, acc1b = {};

    #pragma unroll 2
    for (int i = 0; i < 16; ++i) {
        const int r = R0 + i;
        const int b0  = swzf(ua) * 4;
        const int b0s = swzf(ua + 8) * 4;
        const int b1  = swzf(ua + 512) * 4;
        const int b1s = swzf(ua + 520) * 4;
        const int va0  = (n >= r) ? b0  : zb0;
        const int va0s = (n >= r) ? b0s : (zb0 + 32);
        uint4 a00 = *(const uint4*)(ldsb + va0);
        uint4 a01 = *(const uint4*)(ldsb + va0s);
        uint4 a10 = *(const uint4*)(ldsb + b1);
        uint4 a11 = *(const uint4*)(ldsb + b1s);

        const uint* kl = (const uint*)(ldsb + kb);
        const uint* kh = (const uint*)(ldsb + kbh);
        uint4 b00 = {kh[0], kh[1], kh[2],  kh[3]};
        uint4 b01 = {kh[8], kh[9], kh[10], kh[11]};
        uint4 b10 = {kl[0], kl[1], kl[2],  kl[3]};
        uint4 b11 = {kl[8], kl[9], kl[10], kl[11]};

        acc0  = MFMA(a00, b00, acc0);
        acc1a = MFMA(a10, b00, acc1a);
        acc0  = MFMA(a01, b01, acc0);
        acc1a = MFMA(a11, b01, acc1a);
        acc1b = MFMA(a00, b10, acc1b);
        acc1b = MFMA(a01, b11, acc1b);

        ua  -= 16; kb -= 64; kbh -= 64;
    }
    __syncthreads();

    f32x16 part_send, part_keep;
    if (wv == 0) { part_send = acc1a + acc1b; part_keep = acc0; }
    else         { part_send = acc0;          part_keep = acc1a + acc1b; }
    const int exw = (wv == 0) ? 1024 : 2048;
    const int exr = (wv == 0) ? 2048 : 1024;
    #pragma unroll
    for (int q = 0; q < 4; ++q) {
        float4 f = {part_send[4*q], part_send[4*q+1], part_send[4*q+2], part_send[4*q+3]};
        *(float4*)&lds[exw + q * 256 + 4 * l] = f;
    }
    __syncthreads();
    f32x16 tile = part_keep;
    #pragma unroll
    for (int q = 0; q < 4; ++q) {
        float4 f = *(const float4*)&lds[exr + q * 256 + 4 * l];
        tile[4*q] += f.x; tile[4*q+1] += f.y; tile[4*q+2] += f.z; tile[4*q+3] += f.w;
    }

    #pragma unroll
    for (int t = 0; t < 16; ++t) {
        const int rloc = (t & 3) + 8 * (t >> 2) + 4 * hi;
        const int p = 32 * wv + rloc;
        const uint w = lds[swzf(16 * p + (n >> 1))];
        const float xr = __uint_as_float((n & 1) ? (w & 0xffff0000u) : (w << 16));
        out[rb + (size_t)p * 32 + n] = tile[t] + xr + bv;
    }
}

extern "C" void kernel_launch(void* const* d_in, const int* in_sizes, int n_in,
                              void* d_out, int out_size, void* d_ws, size_t ws_size,
                              hipStream_t stream) {
    const float* x    = (const float*)d_in[0];   // (4, 2048, 2048) f32
    const float* kern = (const float*)d_in[1];   // (4, 2048, 2048) f32
    const float* bias = (const float*)d_in[2];   // (2048,) f32
    float* out = (float*)d_out;                  // (4, 2048, 2048) f32

    const size_t need = (size_t)8192 * 4096;     // 32 MB bf16-x staging
    if (ws_size >= need) {
        hipLaunchKernelGGL(hyena_vmem, dim3(8192), dim3(128), 0, stream,
                           x, kern, bias, out, (char*)d_ws);
    } else {
        hipLaunchKernelGGL(hyena_lds, dim3(8192), dim3(128), 0, stream,
                           x, kern, bias, out);
    }
}

// Round 14
// 60.112 us; speedup vs baseline: 1.2792x; 1.2792x over previous
//
#include <hip/hip_runtime.h>

typedef __attribute__((ext_vector_type(8)))  short short8;
typedef __attribute__((ext_vector_type(16))) float f32x16;
typedef unsigned int uint;

#define SEQ   2048
#define KB0   1024                 // x flat bf16: u32 [0,1024); then 2 krev parity copies
#define KSTR2 1040                 // u32 per copy (reads reach m=1038)
#define KB1   (KB0 + KSTR2)        // 2064: odd-parity copy
#define ZB    (KB0 + 2 * KSTR2)    // 3104: 16-u32 zero region (broadcast reads)
#define LDSU  (ZB + 16)            // 3120 u32 = 12480 B -> high occupancy

__device__ inline uint pack2(float lo, float hi_) {
    uint ul = __float_as_uint(lo), uh = __float_as_uint(hi_);
    ul = (ul + 0x7fffu + ((ul >> 16) & 1u)) >> 16;   // RNE f32->bf16
    uh = (uh + 0x7fffu + ((uh >> 16) & 1u)) >> 16;
    return (ul & 0xffffu) | (uh << 16);
}

// XOR-swizzle on u32 index: bits 2-4 ^= bits 5-7 (bijective, b128-safe).
__device__ inline int swz(int v) { return v ^ ((v >> 3) & 28); }

#define MFMA(A, B, C) __builtin_amdgcn_mfma_f32_32x32x16_bf16( \
    __builtin_bit_cast(short8, A), __builtin_bit_cast(short8, B), C, 0, 0, 0)

// One 128-thread block (2 waves) per (b,d) row. Wave wv computes r = 16*wv..16*wv+15
// of Y(64x32) = sum_r shift_r(X) * T_r^T (32x32x16 bf16 MFMA); waves exchange partial
// accumulators through LDS, each writes one 32-row output tile.
// A-frags: b128 from flat XOR-swizzled bf16 x. B-frags: 4 consecutive u32 at arbitrary
// index in a parity-matched krev copy -> adjacent ds_read_b32 merge to ds_read2_b32.
__global__ __launch_bounds__(128, 6)
void hyena_mfma(const float* __restrict__ x, const float* __restrict__ kern,
                const float* __restrict__ bias, float* __restrict__ out)
{
    __shared__ __align__(16) uint lds[LDSU];
    char* ldsb = (char*)lds;

    const int tid = threadIdx.x;       // 0..127
    const int wv  = tid >> 6;          // wave id 0,1
    const int l   = tid & 63;
    const int n   = l & 31;            // MFMA row (A) / col (B/D)
    const int hi  = l >> 5;            // k-group half
    const int row = blockIdx.x;        // b*2048 + d
    const size_t rb = (size_t)row * SEQ;
    const float bv = bias[row & 2047];

    // ---- stage x flat as bf16, swizzled (b128 writes, 8 elems/thread) ----
    #pragma unroll
    for (int it = 0; it < 2; ++it) {
        const int e = it * 1024 + 8 * tid;         // 0..2040 step 8
        float4 a = *(const float4*)&x[rb + e];
        float4 b = *(const float4*)&x[rb + e + 4];
        uint4 w = {pack2(a.x, a.y), pack2(a.z, a.w), pack2(b.x, b.y), pack2(b.z, b.w)};
        *(uint4*)&lds[swz(e >> 1)] = w;            // e>>1 mult of 4 -> b128-safe
    }
    // ---- stage 2 krev parity copies: kA[m]=(kr[2m],kr[2m+1]), kB[m]=(kr[2m+1],kr[2m+2])
    #pragma unroll
    for (int it = 0; it < 2; ++it) {
        const int j = it * 1024 + 8 * tid;                    // 0..2040 step 8
        const float* kp0 = &kern[rb + (j == 2040 ? 0 : (2036 - j))];
        const float* kp1 = &kern[rb + (2040 - j)];            // >= rb, 16B-aligned
        float4 f0 = *(const float4*)kp0;                      // (kr[j+11..j+8]) desc
        float4 f1 = *(const float4*)kp1;                      // (kr[j+7..j+4])  desc
        float4 f2 = *(const float4*)(kp1 + 4);                // (kr[j+3..j])    desc
        if (j == 2040) { f0.x = 0.f; f0.y = 0.f; f0.z = 0.f; f0.w = 0.f; }
        const float k0 = f2.w, k1 = f2.z, k2 = f2.y, k3 = f2.x;
        const float k4 = f1.w, k5 = f1.z, k6 = f1.y, k7 = f1.x;
        const float k8 = f0.w;
        const int m = j >> 1;                                 // mult of 4 -> 16B aligned
        uint4 w0 = {pack2(k0,k1), pack2(k2,k3), pack2(k4,k5), pack2(k6,k7)};
        uint4 w1 = {pack2(k1,k2), pack2(k3,k4), pack2(k5,k6), pack2(k7,k8)};
        *(uint4*)&lds[KB0 + m] = w0;
        *(uint4*)&lds[KB1 + m] = w1;
    }
    if (tid < 16) {                    // copy tails (elements >= 2048 are zero) + zeros
        lds[KB0 + 1024 + tid] = 0u;
        lds[KB1 + 1024 + tid] = 0u;
        lds[ZB + tid] = 0u;
    }
    __syncthreads();

    // ---- per-lane bases (wave wv handles r = R0 .. R0+15) ----
    const int R0   = wv << 4;
    const int st00 = 2047 - n + 8 * hi;
    const int par  = st00 & 1;
    int kb  = (KB0 + par * KSTR2 + (st00 >> 1)) * 4 - 2048 - (R0 << 6);  // T_{r+32} base
    int kbh = kb + 2048;                                                 // T_r base
    asm volatile("" : "+v"(kbh));   // independent DS base -> ds_read2_b32 merging
    int ua = 16 * n + 4 * hi - (R0 << 4);         // u32 idx, tile0 s0
    const int zb0 = ZB * 4 + 16 * hi;             // zero region (broadcast)

    f32x16 acc0 = {}, acc1a = {}, acc1b = {};

    #pragma unroll 2
    for (int i = 0; i < 16; ++i) {
        const int r = R0 + i;
        const int b0  = swz(ua) * 4;              // garbage if n<r (unselected)
        const int b0s = swz(ua + 8) * 4;
        const int b1  = swz(ua + 512) * 4;
        const int b1s = swz(ua + 520) * 4;
        const int va0  = (n >= r) ? b0  : zb0;    // A row (n-r) or zeros
        const int va0s = (n >= r) ? b0s : (zb0 + 32);
        uint4 a00 = *(const uint4*)(ldsb + va0);             // A(-r,  s0)
        uint4 a01 = *(const uint4*)(ldsb + va0s);            // A(-r,  s1)
        uint4 a10 = *(const uint4*)(ldsb + b1);              // A(32-r,s0)
        uint4 a11 = *(const uint4*)(ldsb + b1s);             // A(32-r,s1)

        const uint* kl = (const uint*)(ldsb + kb);           // T_{r+32}
        const uint* kh = (const uint*)(ldsb + kbh);          // T_r
        uint4 b00 = {kh[0], kh[1], kh[2],  kh[3]};           // s0
        uint4 b01 = {kh[8], kh[9], kh[10], kh[11]};          // s1
        uint4 b10 = {kl[0], kl[1], kl[2],  kl[3]};
        uint4 b11 = {kl[8], kl[9], kl[10], kl[11]};

        acc0  = MFMA(a00, b00, acc0);    // tile0 += X(-r)   * T_r^T
        acc1a = MFMA(a10, b00, acc1a);   // tile1 += X(32-r) * T_r^T
        acc0  = MFMA(a01, b01, acc0);
        acc1a = MFMA(a11, b01, acc1a);
        acc1b = MFMA(a00, b10, acc1b);   // tile1 += X(-r)   * T_{r+32}^T
        acc1b = MFMA(a01, b11, acc1b);

        ua  -= 16;       // shift: -32 x elements
        kb  -= 64;       // shift: -32 krev elements = -16 u32
        kbh -= 64;
    }
    __syncthreads();     // all k reads done before exchange overwrites copies

    // ---- cross-wave partial exchange: [q][lane] f4 layout ----
    f32x16 part_send, part_keep;
    if (wv == 0) { part_send = acc1a + acc1b; part_keep = acc0; }
    else         { part_send = acc0;          part_keep = acc1a + acc1b; }
    const int exw = (wv == 0) ? 1024 : 2048;
    const int exr = (wv == 0) ? 2048 : 1024;
    #pragma unroll
    for (int q = 0; q < 4; ++q) {
        float4 f = {part_send[4*q], part_send[4*q+1], part_send[4*q+2], part_send[4*q+3]};
        *(float4*)&lds[exw + q * 256 + 4 * l] = f;
    }
    __syncthreads();
    f32x16 tile = part_keep;
    #pragma unroll
    for (int q = 0; q < 4; ++q) {
        float4 f = *(const float4*)&lds[exr + q * 256 + 4 * l];
        tile[4*q] += f.x; tile[4*q+1] += f.y; tile[4*q+2] += f.z; tile[4*q+3] += f.w;
    }

    // ---- epilogue: wave wv writes tile wv; y = acc + x(bf16 from LDS) + bias ----
    #pragma unroll
    for (int t = 0; t < 16; ++t) {
        const int rloc = (t & 3) + 8 * (t >> 2) + 4 * hi;  // verified 32x32 C/D map
        const int p = 32 * wv + rloc;
        const uint w = lds[swz(16 * p + (n >> 1))];
        const float xr = __uint_as_float((n & 1) ? (w & 0xffff0000u) : (w << 16));
        out[rb + (size_t)p * 32 + n] = tile[t] + xr + bv;
    }
}

extern "C" void kernel_launch(void* const* d_in, const int* in_sizes, int n_in,
                              void* d_out, int out_size, void* d_ws, size_t ws_size,
                              hipStream_t stream) {
    const float* x    = (const float*)d_in[0];   // (4, 2048, 2048) f32
    const float* kern = (const float*)d_in[1];   // (4, 2048, 2048) f32
    const float* bias = (const float*)d_in[2];   // (2048,) f32
    float* out = (float*)d_out;                  // (4, 2048, 2048) f32

    hipLaunchKernelGGL(hyena_mfma, dim3(4 * 2048), dim3(128), 0, stream,
                       x, kern, bias, out);
}